// Round 4
// baseline (315.186 us; speedup 1.0000x reference)
//
#include <hip/hip_runtime.h>

#define NN 100000                  // nodes (< 2^17 — required by 4B packed bin record)
#define NBKT ((NN + 255) / 256)    // 391 dst-buckets of 256 nodes
#define BIN_CHUNK 6272             // ~256 blocks for 1.6M edges

typedef __attribute__((ext_vector_type(4))) float f32x4;
typedef __attribute__((ext_vector_type(2))) float f32x2;
typedef __attribute__((ext_vector_type(8))) __bf16 bf16x8;
typedef __attribute__((ext_vector_type(8))) unsigned short u16x8;
typedef __attribute__((ext_vector_type(4))) unsigned short u16x4;

__device__ __forceinline__ unsigned short f2bf(float f) {
  unsigned u = __builtin_bit_cast(unsigned, f);
  u = (u + 0x7FFFu + ((u >> 16) & 1u)) >> 16;   // RNE
  return (unsigned short)u;
}
__device__ __forceinline__ float bflo(unsigned v) {
  return __builtin_bit_cast(float, v << 16);
}
__device__ __forceinline__ float bfhi(unsigned v) {
  return __builtin_bit_cast(float, v & 0xFFFF0000u);
}

// int64 edge_index has zero high words (node ids < 2^17, prob of false-negative ~1e-40)
__device__ __forceinline__ int self_flag(const void* ei) {
  const unsigned* e = (const unsigned*)ei;
  int i64 = 1;
  for (int k = 0; k < 8; ++k)
    if (e[2 * k + 1] != 0u) i64 = 0;
  return i64;
}
__device__ __forceinline__ int edge_at(const void* ei, int flag, size_t idx) {
  if (flag) return (int)((const long long*)ei)[idx];
  return ((const int*)ei)[idx];
}

// ==== k_front: weight prep + bucket histogram + (last block) bucket scan ====
// ticket lives at bcnt[504]; bcnt[0..511] zeroed by hipMemsetAsync before launch.
__global__ __launch_bounds__(256) void k_front(const float* W1l, const float* W1r,
                                               const float* W2l, const float* W2r,
                                               unsigned short* Wc1, unsigned short* Wc2,
                                               const void* ei, int* bcnt, int* bbase,
                                               int* gcur, int ne, int nb) {
  __shared__ int h[512];
  __shared__ int s[512];
  __shared__ int amLast;
  const int t = threadIdx.x;
  const int f = self_flag(ei);

  // weight combine/cast (blocks 0..63 cover 16384 entries)
  int i = blockIdx.x * 256 + t;
  if (i < 128 * 128) {
    int c = i >> 7, k = i & 127;
    float v = (c < 64) ? W1l[c * 128 + k] : W1r[(c - 64) * 128 + k];
    Wc1[i] = f2bf(v);
  }
  if (i < 64 * 64) {
    int c = i >> 6, k = i & 63;
    float v = (c < 32) ? W2l[c * 64 + k] : W2r[(c - 32) * 64 + k];
    Wc2[i] = f2bf(v);
  }

  for (int j = t; j < nb; j += 256) h[j] = 0;
  __syncthreads();
  for (int e = blockIdx.x * 256 + t; e < ne; e += gridDim.x * 256) {
    int d = edge_at(ei, f, (size_t)ne + e);
    atomicAdd(&h[d >> 8], 1);
  }
  __syncthreads();
  for (int j = t; j < nb; j += 256)
    if (h[j]) atomicAdd(&bcnt[j], h[j]);
  __threadfence();
  if (t == 0) amLast = (atomicAdd(&bcnt[504], 1) == (int)gridDim.x - 1);
  __syncthreads();
  if (amLast) {
    __threadfence();
    // coherent (device-scope atomic) reads of final counts, then 512-wide scan
    int v0 = 0, v1 = 0;
    if (t < nb) v0 = atomicOr(&bcnt[t], 0);
    if (t + 256 < nb) v1 = atomicOr(&bcnt[t + 256], 0);
    s[t] = v0;
    s[t + 256] = v1;
    __syncthreads();
    for (int off = 1; off < 512; off <<= 1) {
      int a = (t >= off) ? s[t - off] : 0;
      int b2 = s[t + 256 - off];
      __syncthreads();
      if (t >= off) s[t] += a;
      s[t + 256] += b2;
      __syncthreads();
    }
    if (t < nb) { bbase[t] = s[t] - v0; gcur[t] = s[t] - v0; }
    if (t + 256 < nb) { bbase[t + 256] = s[t + 256] - v1; gcur[t + 256] = s[t + 256] - v1; }
    if (t == 0) bbase[nb] = ne;
  }
}

// ==== k_bin: bin edges into bucket-contiguous 4B records (LDS-staged) ====
__global__ __launch_bounds__(256) void k_bin(const void* ei, int* gcur, unsigned* binbuf,
                                             int ne, int nb) {
  __shared__ int hist[512];
  __shared__ int base[512];
  __shared__ unsigned rec[BIN_CHUNK];
  __shared__ unsigned short bkt[BIN_CHUNK];
  const int t = threadIdx.x;
  const int f = self_flag(ei);
  const int c0 = blockIdx.x * BIN_CHUNK;
  const int cend = (c0 + BIN_CHUNK < ne) ? c0 + BIN_CHUNK : ne;
  const int cnt = cend - c0;
  for (int j = t; j < nb; j += 256) hist[j] = 0;
  __syncthreads();
  for (int j = t; j < cnt; j += 256) {
    int d = edge_at(ei, f, (size_t)ne + c0 + j);
    int sv = edge_at(ei, f, (size_t)(c0 + j));
    rec[j] = (unsigned)sv | ((unsigned)(d & 255) << 17);
    int b = d >> 8;
    bkt[j] = (unsigned short)b;
    atomicAdd(&hist[b], 1);
  }
  __syncthreads();
  for (int j = t; j < nb; j += 256) {
    int c = hist[j];
    base[j] = c ? atomicAdd(&gcur[j], c) : 0;
    hist[j] = 0;    // reuse as intra-block cursor
  }
  __syncthreads();
  for (int j = t; j < cnt; j += 256) {
    int b = bkt[j];
    int off = atomicAdd(&hist[b], 1);
    binbuf[base[b] + off] = rec[j];
  }
}

// ==== k_mid: blocks [0,nb) CSR-build per bucket; blocks [nb,..) layer-1 GEMM ====
__device__ void dev_build(int* lds, const unsigned* binbuf, const int* bbase,
                          int* rowptr, int* eidx, int n, int nb, int ne) {
  int* sdeg = lds;
  int* soff = lds + 256;
  int* scur = lds + 512;
  const int b = blockIdx.x;
  const int t = threadIdx.x;
  const int base = bbase[b];
  const int cnt = bbase[b + 1] - base;
  sdeg[t] = 0;
  __syncthreads();
  for (int i = t; i < cnt; i += 256) {
    unsigned r = binbuf[base + i];
    atomicAdd(&sdeg[r >> 17], 1);
  }
  __syncthreads();
  int v = sdeg[t];
  soff[t] = v;
  __syncthreads();
  for (int off = 1; off < 256; off <<= 1) {
    int tmp = (t >= off) ? soff[t - off] : 0;
    __syncthreads();
    if (t >= off) soff[t] += tmp;
    __syncthreads();
  }
  int excl = soff[t] - v;
  scur[t] = 0;
  int node = b * 256 + t;
  if (node < n) rowptr[node] = base + excl;
  if (b == nb - 1 && t == 0) rowptr[n] = ne;
  __syncthreads();
  soff[t] = excl;
  __syncthreads();
  for (int i = t; i < cnt; i += 256) {
    unsigned r = binbuf[base + i];
    int dl = r >> 17;
    eidx[base + soff[dl] + atomicAdd(&scur[dl], 1)] = (int)(r & 0x1FFFF);
  }
}

// layer-1 GEMM: Y[n][128] = X[n][128] @ Wc1^T ; cols 0..63 -> Y1l bf16, 64..127 -> Y1r bf16
__device__ void dev_gemm1(unsigned short* smem, const float* X, const unsigned short* Wc,
                          unsigned short* Yl, unsigned short* Yr, int nrows, int bid) {
  constexpr int K = 128, NC = 128, MB = 128, KP = 136;
  unsigned short* xs = smem;             // [128][136]
  unsigned short* wb = smem + MB * KP;   // [128][136]
  const int t = threadIdx.x;
  const int node0 = bid * MB;

  for (int i = t; i < NC * K / 8; i += 256) {
    int r = i / (K / 8), c8 = i % (K / 8);
    u16x8 v = *(const u16x8*)(Wc + r * K + c8 * 8);
    *(u16x8*)(&wb[r * KP + c8 * 8]) = v;
  }
  for (int i = t; i < MB * K / 4; i += 256) {
    int r = i / (K / 4), c4 = i % (K / 4);
    int row = node0 + r;
    f32x4 v = {0.f, 0.f, 0.f, 0.f};
    if (row < nrows) v = *(const f32x4*)(X + (size_t)row * K + c4 * 4);
    u16x4 b;
    b.x = f2bf(v.x); b.y = f2bf(v.y); b.z = f2bf(v.z); b.w = f2bf(v.w);
    *(u16x4*)(&xs[r * KP + c4 * 4]) = b;
  }
  __syncthreads();

  const int w = t >> 6, lane = t & 63;
  const int ln = lane & 15, q = lane >> 4;
  f32x4 acc[2][NC / 16] = {};
#pragma unroll
  for (int kt = 0; kt < K / 32; ++kt) {
    bf16x8 a0 = *(const bf16x8*)(&xs[(w * 32 + ln) * KP + kt * 32 + q * 8]);
    bf16x8 a1 = *(const bf16x8*)(&xs[(w * 32 + 16 + ln) * KP + kt * 32 + q * 8]);
#pragma unroll
    for (int ct = 0; ct < NC / 16; ++ct) {
      bf16x8 b = *(const bf16x8*)(&wb[(ct * 16 + ln) * KP + kt * 32 + q * 8]);
      acc[0][ct] = __builtin_amdgcn_mfma_f32_16x16x32_bf16(a0, b, acc[0][ct], 0, 0, 0);
      acc[1][ct] = __builtin_amdgcn_mfma_f32_16x16x32_bf16(a1, b, acc[1][ct], 0, 0, 0);
    }
  }
  // D layout: col=lane&15, row=(lane>>4)*4+reg  [m89/m91 verified]
#pragma unroll
  for (int nt = 0; nt < 2; ++nt)
#pragma unroll
    for (int ct = 0; ct < NC / 16; ++ct) {
      int row0 = node0 + w * 32 + nt * 16 + q * 4;
      int col = ct * 16 + ln;
#pragma unroll
      for (int r = 0; r < 4; ++r) {
        int row = row0 + r;
        if (row < nrows) {
          unsigned short v = f2bf(acc[nt][ct][r]);
          if (ct < NC / 32) Yl[(size_t)row * 64 + col] = v;
          else Yr[(size_t)row * 64 + col - 64] = v;
        }
      }
    }
}

__global__ __launch_bounds__(256) void k_mid(const unsigned* binbuf, const int* bbase,
                                             int* rowptr, int* eidx, const float* x,
                                             const unsigned short* Wc1,
                                             unsigned short* Y1l, unsigned short* Y1r,
                                             int n, int nb, int ne) {
  __shared__ __align__(16) unsigned short smem[2 * 128 * 136];
  if (blockIdx.x < (unsigned)nb)
    dev_build((int*)smem, binbuf, bbase, rowptr, eidx, n, nb, ne);
  else
    dev_gemm1(smem, x, Wc1, Y1l, Y1r, n, blockIdx.x - nb);
}

// ==== k_l1: fused layer-1 aggregate (+bias+r+relu) -> LDS h -> layer-2 GEMM ====
// block = 256 thr / 4 waves handles 64 nodes; wave owns 16 nodes.
__global__ __launch_bounds__(256) void k_l1(const unsigned* Y1l, const unsigned* Y1rp,
                                            const int* rowptr, const int* eidx,
                                            const float* b1, const unsigned* Wc2u,
                                            unsigned short* Y2l, unsigned short* Y2r,
                                            int n) {
  __shared__ __align__(16) unsigned short hs[64 * 72];  // [64 nodes][64 bf16 + pad8]
  __shared__ __align__(16) unsigned short wb[64 * 72];
  const int t = threadIdx.x, w = t >> 6, lane = t & 63;
  const int half = lane >> 5, l5 = lane & 31;
  const int base = blockIdx.x * 64;

  // stage Wc2 (64x64 bf16) as u32 pairs into padded rows
  for (int i = t; i < 64 * 32; i += 256) {
    int c = i >> 5, k2 = i & 31;
    ((unsigned*)wb)[c * 36 + k2] = Wc2u[i];
  }

  // Phase A: gather-mean + bias + r-term + relu -> hs
  for (int rep = 0; rep < 16; ++rep) {
    int nl = w * 16 + rep;
    int gid = base + nl;
    unsigned packed = 0;
    if (gid < n) {
      int beg = rowptr[gid], end = rowptr[gid + 1];
      float a0 = 0.f, a1 = 0.f;
      int j = beg + half;
      for (; j + 6 < end; j += 8) {   // 4 gathers in flight per half-wave
        int s0 = eidx[j], s1 = eidx[j + 2], s2 = eidx[j + 4], s3 = eidx[j + 6];
        unsigned v0 = Y1l[(size_t)s0 * 32 + l5];
        unsigned v1 = Y1l[(size_t)s1 * 32 + l5];
        unsigned v2 = Y1l[(size_t)s2 * 32 + l5];
        unsigned v3 = Y1l[(size_t)s3 * 32 + l5];
        a0 += (bflo(v0) + bflo(v1)) + (bflo(v2) + bflo(v3));
        a1 += (bfhi(v0) + bfhi(v1)) + (bfhi(v2) + bfhi(v3));
      }
      for (; j < end; j += 2) {
        unsigned v = Y1l[(size_t)eidx[j] * 32 + l5];
        a0 += bflo(v);
        a1 += bfhi(v);
      }
      a0 += __shfl_xor(a0, 32);
      a1 += __shfl_xor(a1, 32);
      int deg = end - beg;
      float inv = deg > 0 ? 1.f / (float)deg : 0.f;
      unsigned r01 = Y1rp[(size_t)gid * 32 + l5];
      f32x2 bb = *(const f32x2*)(b1 + 2 * l5);
      float v0 = a0 * inv + bb.x + bflo(r01);
      float v1 = a1 * inv + bb.y + bfhi(r01);
      v0 = v0 > 0.f ? v0 : 0.f;
      v1 = v1 > 0.f ? v1 : 0.f;
      packed = (unsigned)f2bf(v0) | ((unsigned)f2bf(v1) << 16);
    }
    if (lane < 32) ((unsigned*)hs)[nl * 36 + l5] = packed;
  }
  __syncthreads();

  // Phase B: 64x64x64 GEMM; wave handles 16-row strip
  const int ln = lane & 15, q = lane >> 4;
  f32x4 acc[4] = {};
#pragma unroll
  for (int kt = 0; kt < 2; ++kt) {
    bf16x8 a = *(const bf16x8*)(&hs[(w * 16 + ln) * 72 + kt * 32 + q * 8]);
#pragma unroll
    for (int ct = 0; ct < 4; ++ct) {
      bf16x8 b = *(const bf16x8*)(&wb[(ct * 16 + ln) * 72 + kt * 32 + q * 8]);
      acc[ct] = __builtin_amdgcn_mfma_f32_16x16x32_bf16(a, b, acc[ct], 0, 0, 0);
    }
  }
#pragma unroll
  for (int ct = 0; ct < 4; ++ct) {
    int col = ct * 16 + ln;
#pragma unroll
    for (int r = 0; r < 4; ++r) {
      int gid = base + w * 16 + q * 4 + r;
      if (gid < n) {
        unsigned short v = f2bf(acc[ct][r]);
        if (col < 32) Y2l[(size_t)gid * 32 + col] = v;
        else Y2r[(size_t)gid * 32 + col - 32] = v;
      }
    }
  }
}

// ==== k_agg2: layer-2 aggregate + bias + r-term + log_softmax -> out ====
__global__ __launch_bounds__(256) void k_agg2(const unsigned* Y2l, const unsigned* Y2rp,
                                              const int* rowptr, const int* eidx,
                                              const float* b2, float* out, int n) {
  int gid = blockIdx.x * 4 + (threadIdx.x >> 6);
  int lane = threadIdx.x & 63;
  if (gid >= n) return;
  int beg = rowptr[gid], end = rowptr[gid + 1];
  int grp = lane >> 4, l4 = lane & 15;
  float a0 = 0.f, a1 = 0.f;
  int j = beg + grp;
  for (; j + 4 < end; j += 8) {
    int s0 = eidx[j], s1 = eidx[j + 4];
    unsigned v0 = Y2l[(size_t)s0 * 16 + l4];
    unsigned v1 = Y2l[(size_t)s1 * 16 + l4];
    a0 += bflo(v0) + bflo(v1);
    a1 += bfhi(v0) + bfhi(v1);
  }
  for (; j < end; j += 4) {
    unsigned v = Y2l[(size_t)eidx[j] * 16 + l4];
    a0 += bflo(v);
    a1 += bfhi(v);
  }
  a0 += __shfl_xor(a0, 32); a0 += __shfl_xor(a0, 16);
  a1 += __shfl_xor(a1, 32); a1 += __shfl_xor(a1, 16);
  int deg = end - beg;
  float inv = deg > 0 ? 1.f / (float)deg : 0.f;
  unsigned r01 = Y2rp[(size_t)gid * 16 + l4];
  f32x2 bb = *(const f32x2*)(b2 + 2 * l4);
  float v0 = a0 * inv + bb.x + bflo(r01);
  float v1 = a1 * inv + bb.y + bfhi(r01);
  float m = fmaxf(v0, v1);
#pragma unroll
  for (int off = 8; off; off >>= 1) m = fmaxf(m, __shfl_xor(m, off));
  float e0 = __expf(v0 - m), e1 = __expf(v1 - m);
  float ss = e0 + e1;
#pragma unroll
  for (int off = 8; off; off >>= 1) ss += __shfl_xor(ss, off);
  float lg = __logf(ss);
  if (lane < 16) {
    f32x2 o = {v0 - m - lg, v1 - m - lg};
    *(f32x2*)(out + (size_t)gid * 32 + 2 * l4) = o;
  }
}

extern "C" void kernel_launch(void* const* d_in, const int* in_sizes, int n_in,
                              void* d_out, int out_size, void* d_ws, size_t ws_size,
                              hipStream_t stream) {
  const float* x = (const float*)d_in[0];
  const void* ei = d_in[1];
  const float* W1l = (const float*)d_in[2];
  const float* b1 = (const float*)d_in[3];
  const float* W1r = (const float*)d_in[4];
  const float* W2l = (const float*)d_in[5];
  const float* b2 = (const float*)d_in[6];
  const float* W2r = (const float*)d_in[7];
  const int n = NN;
  const int ne = in_sizes[1] / 2;
  const int nb = NBKT;

  char* base = (char*)d_ws;
  size_t off = 0;
  auto alloc = [&](size_t bytes) -> void* {
    void* r = base + off;
    off = (off + bytes + 255) & ~(size_t)255;
    return r;
  };
  int* bcnt = (int*)alloc(512 * 4);          // counts + ticket at [504]
  int* bbase = (int*)alloc(512 * 4);
  int* gcur = (int*)alloc(512 * 4);
  unsigned* binbuf = (unsigned*)alloc((size_t)ne * 4);
  int* rowptr = (int*)alloc((size_t)(n + 1) * 4);
  int* eidx = (int*)alloc((size_t)ne * 4);
  unsigned short* Wc1 = (unsigned short*)alloc(128 * 128 * 2);
  unsigned short* Wc2 = (unsigned short*)alloc(64 * 64 * 2);
  unsigned short* Y1l = (unsigned short*)alloc((size_t)n * 64 * 2);  // bf16 gather table
  unsigned short* Y1r = (unsigned short*)alloc((size_t)n * 64 * 2);  // bf16 root term
  unsigned short* Y2l = (unsigned short*)alloc((size_t)n * 32 * 2);
  unsigned short* Y2r = (unsigned short*)alloc((size_t)n * 32 * 2);
  if (off > ws_size) return;

  hipMemsetAsync(bcnt, 0, 512 * 4, stream);
  k_front<<<512, 256, 0, stream>>>(W1l, W1r, W2l, W2r, Wc1, Wc2, ei, bcnt, bbase,
                                   gcur, ne, nb);
  k_bin<<<(ne + BIN_CHUNK - 1) / BIN_CHUNK, 256, 0, stream>>>(ei, gcur, binbuf, ne, nb);
  k_mid<<<nb + (n + 127) / 128, 256, 0, stream>>>(binbuf, bbase, rowptr, eidx, x, Wc1,
                                                  Y1l, Y1r, n, nb, ne);
  k_l1<<<(n + 63) / 64, 256, 0, stream>>>((const unsigned*)Y1l, (const unsigned*)Y1r,
                                          rowptr, eidx, b1, (const unsigned*)Wc2,
                                          Y2l, Y2r, n);
  k_agg2<<<(n + 3) / 4, 256, 0, stream>>>((const unsigned*)Y2l, (const unsigned*)Y2r,
                                          rowptr, eidx, b2, (float*)d_out, n);
}